// Round 6
// baseline (339.702 us; speedup 1.0000x reference)
//
#include <hip/hip_runtime.h>

#define B_   2
#define S_   2048
#define D_   2048
#define HQ_  16
#define HKV_ 4
#define HD_  128

typedef __attribute__((ext_vector_type(4))) float f32x4;
typedef __attribute__((ext_vector_type(16))) float f32x16;
typedef __attribute__((ext_vector_type(4))) short s16x4;
typedef __attribute__((ext_vector_type(8))) short s16x8;

static __device__ __forceinline__ ushort f2bf(float f) {
  uint32_t u = __float_as_uint(f);
  u += 0x7fffu + ((u >> 16) & 1u);   // RNE
  return (ushort)(u >> 16);
}

static __device__ __forceinline__ void gload16(const ushort* g, ushort* l) {
  __builtin_amdgcn_global_load_lds((const __attribute__((address_space(1))) uint32_t*)(g),
                                   (__attribute__((address_space(3))) uint32_t*)(l), 16, 0, 0);
}

// ---------------- fp32 -> bf16 cast ----------------
__global__ void cast_kernel(const float* __restrict__ in, ushort* __restrict__ out, int n) {
  int i = (blockIdx.x * blockDim.x + threadIdx.x) * 4;
  if (i + 3 < n) {
    float4 v = *(const float4*)(in + i);
    *(ushort4*)(out + i) = make_ushort4(f2bf(v.x), f2bf(v.y), f2bf(v.z), f2bf(v.w));
  }
}

// ---------------- GEMM 256x256 8-phase: C[M][N] (f32) = A[M][K] * B[N][K]^T ----------------
// BM=BN=256, BK=64, 8 waves (2Mx4N), 512 thr. Double-buffered LDS (128KB), counted vmcnt(4)
// at tile boundaries only (T4), raw s_barrier (no __syncthreads vmcnt-drain), T5 setprio.
// Race-free staging: B(t+1)->other buf in ph0/ph1; A(t+2)->current buf in ph2/ph3 (all A reads
// of tile t complete before ph1-end barrier). Zero-conflict chunk-XOR swizzle.
__global__ __launch_bounds__(512, 2) void gemm256(const ushort* __restrict__ A,
                                                  const ushort* __restrict__ Bm,
                                                  float* __restrict__ C,
                                                  int M, int N, int K, int nbx) {
  __shared__ ushort As[2][16384];   // [buf][256 rows][64 k]
  __shared__ ushort Bs[2][16384];
  const int nwg = gridDim.x;
  const int per = nwg >> 3;
  const int id = blockIdx.x;
  const int wg = (id & 7) * per + (id >> 3);
  const int bx = wg % nbx, by = wg / nbx;
  const int tid = threadIdx.x, lane = tid & 63, wave = tid >> 6;
  const int lrow = lane & 15, lgrp = lane >> 4;
  const int wr = wave >> 2, wc = wave & 3;
  const int brow = by * 256, bcol = bx * 256;
  const int NT = K >> 6;

  const ushort* Abase = A + (size_t)brow * K;
  const ushort* Bbase = Bm + (size_t)bcol * K;

  f32x4 acc[8][4];
#pragma unroll
  for (int i = 0; i < 8; ++i)
#pragma unroll
    for (int j = 0; j < 4; ++j) acc[i][j] = (f32x4){0.f, 0.f, 0.f, 0.f};

  s16x8 aF[8][2], bF[4][2];

#define LDA8(BUF, row, kc) (*(const s16x8*)&As[BUF][(row) * 64 + (((kc) * 32 + lgrp * 8) ^ (((row) & 7) << 3))])
#define LDB8(BUF, row, kc) (*(const s16x8*)&Bs[BUF][(row) * 64 + (((kc) * 32 + lgrp * 8) ^ (((row) & 7) << 3))])

#define STAGE_AH(BUF, H, KT)                                                        \
  {                                                                                 \
    _Pragma("unroll")                                                               \
    for (int i_ = 0; i_ < 2; ++i_) {                                                \
      const int s_ = i_ * 512 + tid;                                                \
      const int r_ = s_ >> 3;                                                       \
      const int cc_ = (s_ & 7) ^ (r_ & 7);                                          \
      gload16(Abase + (size_t)((H) * 128 + r_) * K + (KT) * 64 + cc_ * 8,           \
              &As[BUF][(H) * 8192 + i_ * 4096 + wave * 512]);                       \
    }                                                                               \
  }
#define STAGE_BH(BUF, H, KT)                                                        \
  {                                                                                 \
    _Pragma("unroll")                                                               \
    for (int i_ = 0; i_ < 2; ++i_) {                                                \
      const int s_ = i_ * 512 + tid;                                                \
      const int r_ = s_ >> 3;                                                       \
      const int cc_ = (s_ & 7) ^ (r_ & 7);                                          \
      gload16(Bbase + (size_t)((H) * 128 + r_) * K + (KT) * 64 + cc_ * 8,           \
              &Bs[BUF][(H) * 8192 + i_ * 4096 + wave * 512]);                       \
    }                                                                               \
  }

#define TILE(BUF, J, VMS)                                                           \
  {                                                                                 \
    asm volatile("s_waitcnt " VMS ::: "memory");                                    \
    __builtin_amdgcn_s_barrier();                                                   \
    /* ph0: A mh0 + B nt01 reads; stage B(t+1) half0 */                             \
    _Pragma("unroll")                                                               \
    for (int mt = 0; mt < 4; ++mt) {                                                \
      const int row = wr * 128 + mt * 16 + lrow;                                    \
      aF[mt][0] = LDA8(BUF, row, 0);                                                \
      aF[mt][1] = LDA8(BUF, row, 1);                                                \
    }                                                                               \
    _Pragma("unroll")                                                               \
    for (int nt = 0; nt < 2; ++nt) {                                                \
      const int row = wc * 64 + nt * 16 + lrow;                                     \
      bF[nt][0] = LDB8(BUF, row, 0);                                                \
      bF[nt][1] = LDB8(BUF, row, 1);                                                \
    }                                                                               \
    if ((J) + 1 < NT) STAGE_BH((BUF) ^ 1, 0, (J) + 1);                              \
    __builtin_amdgcn_s_setprio(1);                                                  \
    _Pragma("unroll")                                                               \
    for (int mt = 0; mt < 4; ++mt)                                                  \
      _Pragma("unroll")                                                             \
      for (int nt = 0; nt < 2; ++nt) {                                              \
        acc[mt][nt] = __builtin_amdgcn_mfma_f32_16x16x32_bf16(aF[mt][0], bF[nt][0], acc[mt][nt], 0, 0, 0); \
        acc[mt][nt] = __builtin_amdgcn_mfma_f32_16x16x32_bf16(aF[mt][1], bF[nt][1], acc[mt][nt], 0, 0, 0); \
      }                                                                             \
    __builtin_amdgcn_s_setprio(0);                                                  \
    __builtin_amdgcn_s_barrier();                                                   \
    /* ph1: A mh1 + B nt23 reads; stage B(t+1) half1 */                             \
    _Pragma("unroll")                                                               \
    for (int mt = 0; mt < 4; ++mt) {                                                \
      const int row = wr * 128 + (mt + 4) * 16 + lrow;                              \
      aF[mt + 4][0] = LDA8(BUF, row, 0);                                            \
      aF[mt + 4][1] = LDA8(BUF, row, 1);                                            \
    }                                                                               \
    _Pragma("unroll")                                                               \
    for (int nt = 2; nt < 4; ++nt) {                                                \
      const int row = wc * 64 + nt * 16 + lrow;                                     \
      bF[nt][0] = LDB8(BUF, row, 0);                                                \
      bF[nt][1] = LDB8(BUF, row, 1);                                                \
    }                                                                               \
    if ((J) + 1 < NT) STAGE_BH((BUF) ^ 1, 1, (J) + 1);                              \
    __builtin_amdgcn_s_setprio(1);                                                  \
    _Pragma("unroll")                                                               \
    for (int mt = 0; mt < 4; ++mt)                                                  \
      _Pragma("unroll")                                                             \
      for (int nt = 0; nt < 2; ++nt) {                                              \
        acc[mt + 4][nt] = __builtin_amdgcn_mfma_f32_16x16x32_bf16(aF[mt + 4][0], bF[nt][0], acc[mt + 4][nt], 0, 0, 0); \
        acc[mt + 4][nt] = __builtin_amdgcn_mfma_f32_16x16x32_bf16(aF[mt + 4][1], bF[nt][1], acc[mt + 4][nt], 0, 0, 0); \
      }                                                                             \
    __builtin_amdgcn_s_setprio(0);                                                  \
    __builtin_amdgcn_s_barrier();                                                   \
    /* ph2: stage A(t+2) half0 into CURRENT buf (A reads all done); MFMA mh0 x nt23 */ \
    if ((J) + 2 < NT) STAGE_AH(BUF, 0, (J) + 2);                                    \
    __builtin_amdgcn_s_setprio(1);                                                  \
    _Pragma("unroll")                                                               \
    for (int mt = 0; mt < 4; ++mt)                                                  \
      _Pragma("unroll")                                                             \
      for (int nt = 2; nt < 4; ++nt) {                                              \
        acc[mt][nt] = __builtin_amdgcn_mfma_f32_16x16x32_bf16(aF[mt][0], bF[nt][0], acc[mt][nt], 0, 0, 0); \
        acc[mt][nt] = __builtin_amdgcn_mfma_f32_16x16x32_bf16(aF[mt][1], bF[nt][1], acc[mt][nt], 0, 0, 0); \
      }                                                                             \
    __builtin_amdgcn_s_setprio(0);                                                  \
    /* ph3: stage A(t+2) half1; MFMA mh1 x nt23 */                                  \
    if ((J) + 2 < NT) STAGE_AH(BUF, 1, (J) + 2);                                    \
    __builtin_amdgcn_s_setprio(1);                                                  \
    _Pragma("unroll")                                                               \
    for (int mt = 0; mt < 4; ++mt)                                                  \
      _Pragma("unroll")                                                             \
      for (int nt = 2; nt < 4; ++nt) {                                              \
        acc[mt + 4][nt] = __builtin_amdgcn_mfma_f32_16x16x32_bf16(aF[mt + 4][0], bF[nt][0], acc[mt + 4][nt], 0, 0, 0); \
        acc[mt + 4][nt] = __builtin_amdgcn_mfma_f32_16x16x32_bf16(aF[mt + 4][1], bF[nt][1], acc[mt + 4][nt], 0, 0, 0); \
      }                                                                             \
    __builtin_amdgcn_s_setprio(0);                                                  \
  }

  // prologue: tile0 fully + tile1 A-halves -> 12 loads/thread; vmcnt(4) at tile0 leaves A(t1) in flight
  STAGE_AH(0, 0, 0); STAGE_AH(0, 1, 0); STAGE_BH(0, 0, 0); STAGE_BH(0, 1, 0);
  STAGE_AH(1, 0, 1); STAGE_AH(1, 1, 1);

#pragma unroll 1
  for (int j = 0; j < NT - 2; j += 2) {
    TILE(0, j, "vmcnt(4)");
    TILE(1, j + 1, "vmcnt(4)");
  }
  TILE(0, NT - 2, "vmcnt(4)");
  TILE(1, NT - 1, "vmcnt(0)");

#undef TILE
#undef STAGE_AH
#undef STAGE_BH
#undef LDA8
#undef LDB8

#pragma unroll
  for (int mt = 0; mt < 8; ++mt) {
#pragma unroll
    for (int nt = 0; nt < 4; ++nt) {
      const int row = brow + wr * 128 + mt * 16 + lgrp * 4;
      const int col = bcol + wc * 64 + nt * 16 + lrow;
#pragma unroll
      for (int rr = 0; rr < 4; ++rr)
        C[(size_t)(row + rr) * N + col] = acc[mt][nt][rr];
    }
  }
}

// ---------------- RoPE on Q and K (Q pre-scaled by log2(e)/sqrt(hd)) ----------------
// One sincos per (b,s,i); loop over all 20 heads.
__global__ __launch_bounds__(256) void rope_qk(const float* __restrict__ qkv,
                                               ushort* __restrict__ Qb, ushort* __restrict__ Kb) {
  const int idx = blockIdx.x * 256 + threadIdx.x;   // (b*S+s)*64 + i
  const int i = idx & 63;
  const int t = idx >> 6;
  const int s = t & (S_ - 1);
  const int b = t >> 11;
  const float inv = exp2f(-(float)i * 0.20762050594046832f);  // log2(10000)/64
  float sn, cs;
  sincosf((float)s * inv, &sn, &cs);
  const size_t row = (size_t)t * 3072;
  const float SCL2 = 0.12751744716705736f;   // (1/sqrt(128)) * log2(e)
#pragma unroll
  for (int h = 0; h < HQ_; ++h) {
    const float a  = qkv[row + h * 128 + i];
    const float c2 = qkv[row + h * 128 + i + 64];
    const size_t ob = ((size_t)((b * HQ_ + h) * S_ + s)) * 128;
    Qb[ob + i]      = f2bf((a * cs - c2 * sn) * SCL2);
    Qb[ob + i + 64] = f2bf((c2 * cs + a * sn) * SCL2);
  }
#pragma unroll
  for (int kh = 0; kh < HKV_; ++kh) {
    const float a  = qkv[row + 2048 + kh * 128 + i];
    const float c2 = qkv[row + 2048 + kh * 128 + i + 64];
    const size_t ob = ((size_t)((b * HKV_ + kh) * S_ + s)) * 128;
    Kb[ob + i]      = f2bf(a * cs - c2 * sn);
    Kb[ob + i + 64] = f2bf(c2 * cs + a * sn);
  }
}

// ---------------- V transpose: qkv f32 V-part -> Vt[b][kh][d][s-pi] bf16 ----------------
// pi permutes s within each 16-group (swap bits 2<->3) so PV's A-operand reads are single b128s.
__global__ __launch_bounds__(256) void v_transpose(const float* __restrict__ qkv, ushort* __restrict__ Vt) {
  __shared__ ushort tile[128][72];
  const int s0 = blockIdx.x * 64;
  const int kh = blockIdx.y;
  const int b  = blockIdx.z;
  for (int idx = threadIdx.x; idx < 64 * 128; idx += 256) {
    int sl = idx >> 7;
    int d  = idx & 127;
    float v = qkv[(size_t)(b * S_ + s0 + sl) * 3072 + 2560 + kh * 128 + d];
    tile[d][sl] = f2bf(v);
  }
  __syncthreads();
  for (int idx = threadIdx.x; idx < 64 * 128; idx += 256) {
    int d  = idx >> 6;
    int sl = idx & 63;
    int sp = (sl & 48) | (sl & 3) | ((sl & 8) >> 1) | ((sl & 4) << 1);  // swap bits 2,3
    Vt[((size_t)(b * HKV_ + kh) * 128 + d) * S_ + s0 + sp] = tile[d][sl];
  }
}

// ---------------- Flash attention (causal, GQA), 32x32x16 MFMA ----------------
// grid (16, HQ, B) = 512 blocks, 256 thr = 4 waves x 32 q-rows (QBLK=128), one q-tile each.
// Mirror balance: qt = b ? 15-x : x. KVBLK=64, double-buffered global_load_lds staging;
// kt-loop unrolled x2; per-read addressing = 1 v_xor with compile-time constant.
__global__ __launch_bounds__(256, 2) void attn_kernel(const ushort* __restrict__ Qb,
                                                      const ushort* __restrict__ Kb,
                                                      const ushort* __restrict__ Vt,
                                                      ushort* __restrict__ Ao) {
  __shared__ ushort Ks[2][64 * 128];
  __shared__ ushort Vs[2][128 * 64];
  const int h = blockIdx.y, b = blockIdx.z, kh = h >> 2;
  const int tid = threadIdx.x, lane = tid & 63, wave = tid >> 6;
  const int lq = lane & 31, g = lane >> 5;
  const ushort* Kg = Kb + ((size_t)(b * HKV_ + kh)) * S_ * HD_;   // [s][128]
  const ushort* Vg = Vt + ((size_t)(b * HKV_ + kh)) * HD_ * S_;   // [d][S] (k-pi within 16)

  const int qt = b ? (15 - (int)blockIdx.x) : (int)blockIdx.x;
  const int q0 = qt * 128;
  const int qg = q0 + wave * 32 + lq;
  const int nk = 2 * qt + 2;

  // resident Q fragments (direct global, once)
  s16x8 qF[8];
  {
    const ushort* qrow = Qb + (((size_t)(b * HQ_ + h)) * S_ + qg) * HD_ + g * 8;
#pragma unroll
    for (int s = 0; s < 8; ++s) qF[s] = *(const s16x8*)(qrow + s * 16);
  }

  // precomputed LDS byte offsets (buffer 0); buffer 1 = +16384 (offset immediate)
  const char* KsB = (const char*)&Ks[0][0];
  const char* VsB = (const char*)&Vs[0][0];
  uint32_t ka[2], va[4];
#pragma unroll
  for (int t = 0; t < 2; ++t) ka[t] = (uint32_t)(t * 32 + lq) * 256 + ((uint32_t)(g ^ (lq & 15)) << 4);
#pragma unroll
  for (int dt = 0; dt < 4; ++dt) va[dt] = (uint32_t)(dt * 32 + lq) * 128 + ((uint32_t)(g ^ (lq & 7)) << 4);

#define STAGE(buf, kt64)                                                          \
    {                                                                             \
      _Pragma("unroll")                                                           \
      for (int i_ = 0; i_ < 4; ++i_) {                                            \
        const int slot = i_ * 256 + tid;                                          \
        const int r = slot >> 4, c = slot & 15;                                   \
        const int cc = c ^ (r & 15);                                              \
        gload16(Kg + ((size_t)((kt64) * 64 + r)) * HD_ + cc * 8,                  \
                &Ks[buf][i_ * 2048 + wave * 512]);                                \
      }                                                                           \
      _Pragma("unroll")                                                           \
      for (int i_ = 0; i_ < 4; ++i_) {                                            \
        const int slot = i_ * 256 + tid;                                          \
        const int r = slot >> 3, c = slot & 7;                                    \
        const int cc = c ^ (r & 7);                                               \
        gload16(Vg + (size_t)r * S_ + (kt64) * 64 + cc * 8,                       \
                &Vs[buf][i_ * 2048 + wave * 512]);                                \
      }                                                                           \
    }

  f32x16 acc[4] = {};
  float m_run = -3.0e38f, l_run = 0.f;

  STAGE(0, 0);
  asm volatile("s_waitcnt vmcnt(0)" ::: "memory");
  __syncthreads();

#define COMPUTE(CUR, ktv)                                                                   \
  {                                                                                         \
    f32x16 sc[2] = {};                                                                      \
    __builtin_amdgcn_s_setprio(1);                                                          \
    _Pragma("unroll")                                                                       \
    for (int s = 0; s < 8; ++s) {                                                           \
      const s16x8 k0 = *(const s16x8*)(KsB + (ka[0] ^ (uint32_t)(s << 5)) + (CUR)*16384);   \
      const s16x8 k1 = *(const s16x8*)(KsB + (ka[1] ^ (uint32_t)(s << 5)) + (CUR)*16384);   \
      sc[0] = __builtin_amdgcn_mfma_f32_32x32x16_bf16(k0, qF[s], sc[0], 0, 0, 0);           \
      sc[1] = __builtin_amdgcn_mfma_f32_32x32x16_bf16(k1, qF[s], sc[1], 0, 0, 0);           \
    }                                                                                       \
    __builtin_amdgcn_s_setprio(0);                                                          \
    float tmax = -3.0e38f;                                                                  \
    if ((ktv) >= 2 * qt) {                                                                  \
      _Pragma("unroll")                                                                     \
      for (int t = 0; t < 2; ++t)                                                           \
        _Pragma("unroll")                                                                   \
        for (int r = 0; r < 16; ++r) {                                                      \
          const int kg = (ktv) * 64 + t * 32 + (r & 3) + 8 * (r >> 2) + 4 * g;              \
          if (kg > qg) sc[t][r] = -3.0e38f;                                                 \
          tmax = fmaxf(tmax, sc[t][r]);                                                     \
        }                                                                                   \
    } else {                                                                                \
      _Pragma("unroll")                                                                     \
      for (int t = 0; t < 2; ++t)                                                           \
        _Pragma("unroll")                                                                   \
        for (int r = 0; r < 16; ++r) tmax = fmaxf(tmax, sc[t][r]);                          \
    }                                                                                       \
    tmax = fmaxf(tmax, __shfl_xor(tmax, 32, 64));                                           \
    if (!__all(tmax <= m_run + 8.f)) {                                                      \
      const float m_new = fmaxf(m_run, tmax);                                               \
      const float alpha = exp2f(m_run - m_new);                                             \
      m_run = m_new;                                                                        \
      l_run *= alpha;                                                                       \
      _Pragma("unroll")                                                                     \
      for (int dt = 0; dt < 4; ++dt)                                                        \
        _Pragma("unroll")                                                                   \
        for (int r = 0; r < 16; ++r) acc[dt][r] *= alpha;                                   \
    }                                                                                       \
    float psum = 0.f;                                                                       \
    uint32_t pk[16];                                                                        \
    _Pragma("unroll")                                                                       \
    for (int t = 0; t < 2; ++t)                                                             \
      _Pragma("unroll")                                                                     \
      for (int i = 0; i < 8; ++i) {                                                         \
        const float e0 = exp2f(sc[t][2 * i]     - m_run);                                   \
        const float e1 = exp2f(sc[t][2 * i + 1] - m_run);                                   \
        psum += e0 + e1;                                                                    \
        asm("v_cvt_pk_bf16_f32 %0, %1, %2" : "=v"(pk[t * 8 + i]) : "v"(e0), "v"(e1));       \
      }                                                                                     \
    psum += __shfl_xor(psum, 32, 64);                                                       \
    l_run += psum;                                                                          \
    __builtin_amdgcn_s_setprio(1);                                                          \
    _Pragma("unroll")                                                                       \
    for (int ks = 0; ks < 4; ++ks) {                                                        \
      union { s16x8 v; uint32_t u[4]; } pb;                                                 \
      _Pragma("unroll")                                                                     \
      for (int j = 0; j < 4; ++j) pb.u[j] = pk[ks * 4 + j];                                 \
      _Pragma("unroll")                                                                     \
      for (int dt = 0; dt < 4; ++dt) {                                                      \
        const s16x8 vA = *(const s16x8*)(VsB + (va[dt] ^ (uint32_t)(ks << 5)) + (CUR)*16384);\
        acc[dt] = __builtin_amdgcn_mfma_f32_32x32x16_bf16(vA, pb.v, acc[dt], 0, 0, 0);      \
      }                                                                                     \
    }                                                                                       \
    __builtin_amdgcn_s_setprio(0);                                                          \
  }

#pragma unroll 1
  for (int kt = 0; kt < nk; kt += 2) {
    STAGE(1, kt + 1);
    COMPUTE(0, kt);
    asm volatile("s_waitcnt vmcnt(0)" ::: "memory");
    __syncthreads();
    if (kt + 2 < nk) STAGE(0, kt + 2);
    COMPUTE(1, kt + 1);
    asm volatile("s_waitcnt vmcnt(0)" ::: "memory");
    __syncthreads();
  }

  // epilogue: O = acc / l ; d = dt*32 + (r&3) + 8*(r>>2) + 4g, q = qg
  const float inv_l = 1.f / l_run;
  ushort* orow = Ao + ((size_t)(b * S_ + qg)) * D_ + h * HD_;
#pragma unroll
  for (int dt = 0; dt < 4; ++dt)
#pragma unroll
    for (int u = 0; u < 4; ++u) {
      ushort4 w;
      w.x = f2bf(acc[dt][4 * u + 0] * inv_l);
      w.y = f2bf(acc[dt][4 * u + 1] * inv_l);
      w.z = f2bf(acc[dt][4 * u + 2] * inv_l);
      w.w = f2bf(acc[dt][4 * u + 3] * inv_l);
      *(ushort4*)(orow + dt * 32 + 8 * u + 4 * g) = w;
    }
#undef STAGE
#undef COMPUTE
}

extern "C" void kernel_launch(void* const* d_in, const int* in_sizes, int n_in,
                              void* d_out, int out_size, void* d_ws, size_t ws_size,
                              hipStream_t stream) {
  const float* x  = (const float*)d_in[0];
  const float* wq = (const float*)d_in[1];
  const float* wk = (const float*)d_in[2];
  const float* wv = (const float*)d_in[3];
  const float* wo = (const float*)d_in[4];
  float* out = (float*)d_out;
  char* ws = (char*)d_ws;

  ushort* xb    = (ushort*)(ws);                  // 16,777,216 B
  ushort* wqkvb = (ushort*)(ws + 16777216);       // 12,582,912 B
  ushort* wob   = (ushort*)(ws + 29360128);       //  8,388,608 B
  float*  qkvf  = (float*) (ws + 37748736);       // 50,331,648 B
  ushort* Qb    = (ushort*)(ws + 88080384);       // 16,777,216 B
  ushort* Kb    = (ushort*)(ws + 104857600);      //  4,194,304 B
  ushort* Vt    = (ushort*)(ws + 109051904);      //  4,194,304 B
  ushort* Ao    = (ushort*)(ws + 113246208);      // 16,777,216 B

  cast_kernel<<<8192, 256, 0, stream>>>(x,  xb, 8388608);
  cast_kernel<<<4096, 256, 0, stream>>>(wq, wqkvb, 4194304);
  cast_kernel<<<1024, 256, 0, stream>>>(wk, wqkvb + 4194304, 1048576);
  cast_kernel<<<1024, 256, 0, stream>>>(wv, wqkvb + 5242880, 1048576);
  cast_kernel<<<4096, 256, 0, stream>>>(wo, wob, 4194304);

  gemm256<<<192, 512, 0, stream>>>(xb, wqkvb, qkvf, 4096, 3072, 2048, 12);
  rope_qk<<<1024, 256, 0, stream>>>(qkvf, Qb, Kb);
  v_transpose<<<dim3(32, 4, 2), 256, 0, stream>>>(qkvf, Vt);
  attn_kernel<<<dim3(16, 16, 2), 256, 0, stream>>>(Qb, Kb, Vt, Ao);
  gemm256<<<128, 512, 0, stream>>>(Ao, wob, out, 4096, 2048, 2048, 8);
}